// Round 7
// baseline (264.358 us; speedup 1.0000x reference)
//
#include <hip/hip_runtime.h>
#include <hip/hip_bf16.h>

#define GPTR(p) ((__attribute__((address_space(1))) void*)(p))
#define LPTR(p) ((__attribute__((address_space(3))) void*)(p))

typedef __attribute__((ext_vector_type(8))) short short8;
typedef __attribute__((ext_vector_type(4))) float f32x4;
typedef __attribute__((ext_vector_type(16))) float f32x16;
typedef unsigned short u16t;
typedef unsigned int u32t;

#define NHEAD 16
#define DK 64
#define NF 1024
#define BB 4
#define TT 2048
#define BT (BB * TT) /* 8192 */

static __device__ __forceinline__ u16t f2bf(float f) {
  union { float f; unsigned u; } c; c.f = f;
  unsigned r = c.u + 0x7fffu + ((c.u >> 16) & 1u);
  return (u16t)(r >> 16);
}

static __device__ __forceinline__ u32t pkbf(float a, float b) {
  float2 ff; ff.x = a; ff.y = b;
  __hip_bfloat162 h2 = __float22bfloat162_rn(ff);
  u32t uu; __builtin_memcpy(&uu, &h2, 4);
  return uu;
}

__global__ void cvt_kernel(const float* __restrict__ src, u16t* __restrict__ dst, int n4) {
  int stride = gridDim.x * blockDim.x;
  for (int i = blockIdx.x * blockDim.x + threadIdx.x; i < n4; i += stride) {
    float4 f = reinterpret_cast<const float4*>(src)[i];
    ushort4 o;
    o.x = f2bf(f.x); o.y = f2bf(f.y); o.z = f2bf(f.z); o.w = f2bf(f.w);
    reinterpret_cast<ushort4*>(dst)[i] = o;
  }
}

// C = (A @ W^T + bias) * 0.125 * log2(e) ; bf16 out, fp32 acc
__launch_bounds__(256, 2)
__global__ void qproj_kernel(const u16t* __restrict__ A, const u16t* __restrict__ W,
                             const float* __restrict__ bias, u16t* __restrict__ C) {
  __shared__ u16t As[128 * 64];
  __shared__ u16t Bs[128 * 64];
  const int tid = threadIdx.x;
  const int m0 = blockIdx.x * 128;
  const int n0 = blockIdx.y * 128;
  const int w = tid >> 6, lane = tid & 63;
  const int wr = (w >> 1) * 64, wc = (w & 1) * 64;
  const int g = lane >> 4, r = lane & 15;

  f32x4 acc[4][4] = {};

  for (int kb = 0; kb < NF; kb += 64) {
    __syncthreads();
#pragma unroll
    for (int i = 0; i < 4; ++i) {
      int c = i * 256 + tid;
      int row = c >> 3, slot = c & 7;
      int gs = slot ^ (row & 7);
      __builtin_amdgcn_global_load_lds(GPTR(A + (size_t)(m0 + row) * NF + kb + gs * 8),
                                       LPTR(As + c * 8), 16, 0, 0);
    }
#pragma unroll
    for (int i = 0; i < 4; ++i) {
      int c = i * 256 + tid;
      int row = c >> 3, slot = c & 7;
      int gs = slot ^ (row & 7);
      __builtin_amdgcn_global_load_lds(GPTR(W + (size_t)(n0 + row) * NF + kb + gs * 8),
                                       LPTR(Bs + c * 8), 16, 0, 0);
    }
    __syncthreads();
#pragma unroll
    for (int kk = 0; kk < 2; ++kk) {
      short8 af[4], bfr[4];
#pragma unroll
      for (int i = 0; i < 4; ++i) {
        int row = wr + i * 16 + r;
        int slot = (4 * kk + g) ^ (row & 7);
        af[i] = *reinterpret_cast<const short8*>(As + row * 64 + slot * 8);
      }
#pragma unroll
      for (int j = 0; j < 4; ++j) {
        int row = wc + j * 16 + r;
        int slot = (4 * kk + g) ^ (row & 7);
        bfr[j] = *reinterpret_cast<const short8*>(Bs + row * 64 + slot * 8);
      }
#pragma unroll
      for (int i = 0; i < 4; ++i)
#pragma unroll
        for (int j = 0; j < 4; ++j)
          acc[i][j] = __builtin_amdgcn_mfma_f32_16x16x32_bf16(af[i], bfr[j], acc[i][j], 0, 0, 0);
    }
  }
#pragma unroll
  for (int i = 0; i < 4; ++i)
#pragma unroll
    for (int j = 0; j < 4; ++j) {
      int grow = m0 + wr + i * 16 + 4 * g;
      int gcol = n0 + wc + j * 16 + r;
      float bv = bias[gcol];
#pragma unroll
      for (int reg = 0; reg < 4; ++reg)
        C[(size_t)(grow + reg) * NF + gcol] = f2bf((acc[i][j][reg] + bv) * 0.18033688f);
    }
}

// Flash attention, swapped-QK^T: 8 waves; block = ONE (b,h) x 512 q-rows (2 q-tiles
// of 256 per staged K/V tile). 256 blocks = 1/CU; K/V fetch bounded by construction.
// KVBLK=128 per barrier pair (2 x 64-kv subtiles). Reg-staged K+V with T14
// issue-early/write-late: next-stage global loads fly during compute; barrier 2
// drains only ds_writes. K-frags/V-frags shared across q-tiles.
// LDS 32KB: K @0 (2 subtiles x 8KB; row kv 128B, 16B-slot s = granule s^P(kv),
//   P(r)=(r+(r>>3))&7, P(r+64)=P(r)); V @16384 (2 x 8KB; row d 128B, 8B-slot s =
//   kv-granule s^(d&15)^((d>>4)&3)).
__launch_bounds__(512, 2)
__global__ void attn_kernel(const u16t* __restrict__ Q, const u16t* __restrict__ K,
                            const u16t* __restrict__ V, const int* __restrict__ mask,
                            float* __restrict__ O) {
  __shared__ __attribute__((aligned(16))) char lds[32768];

  const int tid = threadIdx.x;
  const int lane = tid & 63;
  const int w = tid >> 6;
  const int qc = lane & 31;   // q-col for S^T / d-col for PV output
  const int hi = lane >> 5;
  const int b = blockIdx.x >> 4, h = blockIdx.x & 15;
  const size_t bbase = (size_t)b * TT * NF;
  const int hoff = h * DK;
  const int qrow0 = blockIdx.y * 512 + w * 32;   // q-tile 0; tile 1 at +256

  // Q B-frags (col=q=lane&31, k(d)=16t+8hi+e), both q-tiles, whole kernel
  short8 qa[2][4];
#pragma unroll
  for (int qt = 0; qt < 2; ++qt)
#pragma unroll
    for (int t = 0; t < 4; ++t)
      qa[qt][t] = *reinterpret_cast<const short8*>(
          Q + bbase + (size_t)(qrow0 + 256 * qt + qc) * NF + hoff + 16 * t + 8 * hi);

  f32x16 oacc[2][2] = {};
  float lsumA = 0.f, lsumB = 0.f;

  // K staging: chunk c = tid (subtile0 row tid>>3) and tid+512 (subtile1, +64)
  const int srow = tid >> 3;
  const int ksg = (tid & 7) ^ ((srow + (srow >> 3)) & 7);
  const u16t* Ksrc = K + bbase + (size_t)srow * NF + hoff + ksg * 8;

  // V staging: thread = (Qv = tid>>5, sub = (tid>>4)&1, dq = tid&15)
  const int Qv = tid >> 5, sub = (tid >> 4) & 1, dq = tid & 15;
  const u16t* Vsrc = V + bbase + (size_t)(4 * Qv + 2 * sub) * NF + hoff + 4 * dq;
  const int slotbase = Qv ^ (dq >> 2) ^ (4 * (dq & 3));
  const int wbase = 16384 + 4 * dq * 128 + (slotbase << 3) + 4 * sub;

  const int* msrc = mask + b * TT + lane;

  // read-address bases
  const int P0 = (qc + (qc >> 3)) & 7;
  const int P1 = (P0 + 4) & 7;
  const int kB0 = qc * 128 + ((hi ^ P0) << 4);         // K row qc
  const int kB1 = qc * 128 + 4096 + ((hi ^ P1) << 4);  // K row qc+32
  const int g0 = hi ^ (qc & 15) ^ ((qc >> 4) & 3);
  const int vRb0 = 16384 + qc * 128 + (g0 << 3);              // V col d=qc
  const int vRb1 = 16384 + (qc + 32) * 128 + ((g0 ^ 2) << 3); // V col d=qc+32

  // prologue: stage-0 loads into registers
  short8 kr0 = *reinterpret_cast<const short8*>(Ksrc);
  short8 kr1 = *reinterpret_cast<const short8*>(Ksrc + (size_t)64 * NF);
  uint2 uv0a = *reinterpret_cast<const uint2*>(Vsrc);
  uint2 uv0b = *reinterpret_cast<const uint2*>(Vsrc + NF);
  uint2 uv1a = *reinterpret_cast<const uint2*>(Vsrc + (size_t)64 * NF);
  uint2 uv1b = *reinterpret_cast<const uint2*>(Vsrc + (size_t)65 * NF);
  int mv0 = msrc[0], mv1 = msrc[64];
  Ksrc += (size_t)128 * NF; Vsrc += (size_t)128 * NF; msrc += 128;

  for (int s = 0; s < 16; ++s) {
    __syncthreads();  // prior stage's LDS readers done
    // write K (linear chunks) and V (b64-granule layout) from regs
    *reinterpret_cast<short8*>(lds + tid * 16) = kr0;
    *reinterpret_cast<short8*>(lds + tid * 16 + 8192) = kr1;
    {
      u32t p0 = (uv0a.x & 0xffffu) | (uv0b.x << 16);
      u32t p1 = (uv0a.x >> 16) | (uv0b.x & 0xffff0000u);
      u32t p2 = (uv0a.y & 0xffffu) | (uv0b.y << 16);
      u32t p3 = (uv0a.y >> 16) | (uv0b.y & 0xffff0000u);
      *reinterpret_cast<u32t*>(lds + (wbase ^ 0) + 0) = p0;
      *reinterpret_cast<u32t*>(lds + (wbase ^ 8) + 128) = p1;
      *reinterpret_cast<u32t*>(lds + (wbase ^ 16) + 256) = p2;
      *reinterpret_cast<u32t*>(lds + (wbase ^ 24) + 384) = p3;
      u32t q0 = (uv1a.x & 0xffffu) | (uv1b.x << 16);
      u32t q1 = (uv1a.x >> 16) | (uv1b.x & 0xffff0000u);
      u32t q2 = (uv1a.y & 0xffffu) | (uv1b.y << 16);
      u32t q3 = (uv1a.y >> 16) | (uv1b.y & 0xffff0000u);
      *reinterpret_cast<u32t*>(lds + ((wbase + 8192) ^ 0) + 0) = q0;
      *reinterpret_cast<u32t*>(lds + ((wbase + 8192) ^ 8) + 128) = q1;
      *reinterpret_cast<u32t*>(lds + ((wbase + 8192) ^ 16) + 256) = q2;
      *reinterpret_cast<u32t*>(lds + ((wbase + 8192) ^ 24) + 384) = q3;
    }
    unsigned long long bm0 = __ballot(mv0 != 0);
    unsigned long long bm1 = __ballot(mv1 != 0);
    __syncthreads();  // only ds_writes to drain — fast

    if (s != 15) {  // T14: issue next-stage loads; whole compute phase to land
      kr0 = *reinterpret_cast<const short8*>(Ksrc);
      kr1 = *reinterpret_cast<const short8*>(Ksrc + (size_t)64 * NF);
      uv0a = *reinterpret_cast<const uint2*>(Vsrc);
      uv0b = *reinterpret_cast<const uint2*>(Vsrc + NF);
      uv1a = *reinterpret_cast<const uint2*>(Vsrc + (size_t)64 * NF);
      uv1b = *reinterpret_cast<const uint2*>(Vsrc + (size_t)65 * NF);
      mv0 = msrc[0]; mv1 = msrc[64];
      Ksrc += (size_t)128 * NF; Vsrc += (size_t)128 * NF; msrc += 128;
    }

#pragma unroll
    for (int st = 0; st < 2; ++st) {
      const unsigned long long bm = st ? bm1 : bm0;
      const int rb = st * 8192;
      // QK^T: K-frags shared across both q-tiles
      f32x16 sA0 = {}, sA1 = {}, sB0 = {}, sB1 = {};
#pragma unroll
      for (int t = 0; t < 4; ++t) {
        short8 kf0 = *reinterpret_cast<const short8*>(lds + rb + (kB0 ^ (t << 5)));
        short8 kf1 = *reinterpret_cast<const short8*>(lds + rb + (kB1 ^ (t << 5)));
        sA0 = __builtin_amdgcn_mfma_f32_32x32x16_bf16(kf0, qa[0][t], sA0, 0, 0, 0);
        sA1 = __builtin_amdgcn_mfma_f32_32x32x16_bf16(kf1, qa[0][t], sA1, 0, 0, 0);
        sB0 = __builtin_amdgcn_mfma_f32_32x32x16_bf16(kf0, qa[1][t], sB0, 0, 0, 0);
        sB1 = __builtin_amdgcn_mfma_f32_32x32x16_bf16(kf1, qa[1][t], sB1, 0, 0, 0);
      }
      // softmax + pack + PV per kv-16-slice t; V-frags shared across q-tiles
#pragma unroll
      for (int t = 0; t < 4; ++t) {
        union { u32t u[4]; short8 s; } pA, pB;
        float eA = 0.f, eB = 0.f;
#pragma unroll
        for (int i = 0; i < 4; ++i) {
          const int reg = (t & 1) * 8 + 2 * i;
          const int kva = (reg & 3) + 8 * (reg >> 2) + 4 * hi + 32 * (t >> 1);
          const bool ma = (bm >> kva) & 1ull;
          const bool mb = (bm >> (kva + 1)) & 1ull;
          float xa = ma ? (t < 2 ? sA0[reg] : sA1[reg]) : -100.f;
          float xb = mb ? (t < 2 ? sA0[reg + 1] : sA1[reg + 1]) : -100.f;
          float ya = ma ? (t < 2 ? sB0[reg] : sB1[reg]) : -100.f;
          float yb = mb ? (t < 2 ? sB0[reg + 1] : sB1[reg + 1]) : -100.f;
          xa = __builtin_exp2f(xa); xb = __builtin_exp2f(xb);
          ya = __builtin_exp2f(ya); yb = __builtin_exp2f(yb);
          eA += xa + xb; eB += ya + yb;
          pA.u[i] = pkbf(xa, xb);
          pB.u[i] = pkbf(ya, yb);
        }
        lsumA += eA; lsumB += eB;
        union { uint2 u2[2]; short8 s; } vf0, vf1;
        vf0.u2[0] = *reinterpret_cast<const uint2*>(lds + ((vRb0 + rb) ^ ((4 * t) << 3)));
        vf0.u2[1] = *reinterpret_cast<const uint2*>(lds + ((vRb0 + rb) ^ (((4 * t) ^ 2) << 3)));
        vf1.u2[0] = *reinterpret_cast<const uint2*>(lds + ((vRb1 + rb) ^ ((4 * t) << 3)));
        vf1.u2[1] = *reinterpret_cast<const uint2*>(lds + ((vRb1 + rb) ^ (((4 * t) ^ 2) << 3)));
        oacc[0][0] = __builtin_amdgcn_mfma_f32_32x32x16_bf16(pA.s, vf0.s, oacc[0][0], 0, 0, 0);
        oacc[0][1] = __builtin_amdgcn_mfma_f32_32x32x16_bf16(pA.s, vf1.s, oacc[0][1], 0, 0, 0);
        oacc[1][0] = __builtin_amdgcn_mfma_f32_32x32x16_bf16(pB.s, vf0.s, oacc[1][0], 0, 0, 0);
        oacc[1][1] = __builtin_amdgcn_mfma_f32_32x32x16_bf16(pB.s, vf1.s, oacc[1][1], 0, 0, 0);
      }
    }
  }

  // O[q][d]: C-layout row = (reg&3)+8*(reg>>2)+4hi, col = qc (+32)
#pragma unroll
  for (int qt = 0; qt < 2; ++qt) {
    float lsq = qt ? lsumB : lsumA;
    float lall = lsq + __shfl_xor(lsq, 32, 64);
    float linv = 1.0f / lall;
#pragma unroll
    for (int reg = 0; reg < 16; ++reg) {
      const int crow = (reg & 3) + 8 * (reg >> 2) + 4 * hi;
      float rl = __shfl(linv, crow, 64);
      float* orow = O + bbase + (size_t)(qrow0 + 256 * qt + crow) * NF + hoff + qc;
      orow[0] = oacc[qt][0][reg] * rl;
      orow[32] = oacc[qt][1][reg] * rl;
    }
  }
}

extern "C" void kernel_launch(void* const* d_in, const int* in_sizes, int n_in,
                              void* d_out, int out_size, void* d_ws, size_t ws_size,
                              hipStream_t stream) {
  const float* query = (const float*)d_in[0];
  const float* key   = (const float*)d_in[1];
  const float* value = (const float*)d_in[2];
  const int*   mask  = (const int*)d_in[3];
  const float* Wq    = (const float*)d_in[4];
  const float* bq    = (const float*)d_in[5];
  float* out = (float*)d_out;

  u16t* ws = (u16t*)d_ws;
  u16t* qb = ws;
  u16t* kb = ws + (size_t)8 * 1024 * 1024;
  u16t* vb = ws + (size_t)16 * 1024 * 1024;
  u16t* wb = ws + (size_t)24 * 1024 * 1024;
  u16t* qp = ws + (size_t)25 * 1024 * 1024;

  cvt_kernel<<<2048, 256, 0, stream>>>(query, qb, (BT * NF) / 4);
  cvt_kernel<<<2048, 256, 0, stream>>>(key,   kb, (BT * NF) / 4);
  cvt_kernel<<<2048, 256, 0, stream>>>(value, vb, (BT * NF) / 4);
  cvt_kernel<<<1024, 256, 0, stream>>>(Wq,    wb, (NF * NF) / 4);

  qproj_kernel<<<dim3(BT / 128, NF / 128), 256, 0, stream>>>(qb, wb, bq, qp);
  // grid: x = (b,h), y = q-pair; 4 q-blocks of one (b,h) share an XCD (flat%8 = x%8)
  attn_kernel<<<dim3(BB * NHEAD, TT / 512), 512, 0, stream>>>(qp, kb, vb, mask, out);
}

// Round 8
// 264.068 us; speedup vs baseline: 1.0011x; 1.0011x over previous
//
#include <hip/hip_runtime.h>
#include <hip/hip_bf16.h>

#define GPTR(p) ((__attribute__((address_space(1))) void*)(p))
#define LPTR(p) ((__attribute__((address_space(3))) void*)(p))

typedef __attribute__((ext_vector_type(8))) short short8;
typedef __attribute__((ext_vector_type(4))) float f32x4;
typedef __attribute__((ext_vector_type(16))) float f32x16;
typedef unsigned short u16t;
typedef unsigned int u32t;

#define NHEAD 16
#define DK 64
#define NF 1024
#define BB 4
#define TT 2048
#define BT (BB * TT) /* 8192 */

static __device__ __forceinline__ u16t f2bf(float f) {
  union { float f; unsigned u; } c; c.f = f;
  unsigned r = c.u + 0x7fffu + ((c.u >> 16) & 1u);
  return (u16t)(r >> 16);
}

static __device__ __forceinline__ u32t pkbf(float a, float b) {
  float2 ff; ff.x = a; ff.y = b;
  __hip_bfloat162 h2 = __float22bfloat162_rn(ff);
  u32t uu; __builtin_memcpy(&uu, &h2, 4);
  return uu;
}

__global__ void cvt_kernel(const float* __restrict__ src, u16t* __restrict__ dst, int n4) {
  int stride = gridDim.x * blockDim.x;
  for (int i = blockIdx.x * blockDim.x + threadIdx.x; i < n4; i += stride) {
    float4 f = reinterpret_cast<const float4*>(src)[i];
    ushort4 o;
    o.x = f2bf(f.x); o.y = f2bf(f.y); o.z = f2bf(f.z); o.w = f2bf(f.w);
    reinterpret_cast<ushort4*>(dst)[i] = o;
  }
}

// C = (A @ W^T + bias) * 0.125 * log2(e) ; bf16 out, fp32 acc
__launch_bounds__(256, 2)
__global__ void qproj_kernel(const u16t* __restrict__ A, const u16t* __restrict__ W,
                             const float* __restrict__ bias, u16t* __restrict__ C) {
  __shared__ u16t As[128 * 64];
  __shared__ u16t Bs[128 * 64];
  const int tid = threadIdx.x;
  const int m0 = blockIdx.x * 128;
  const int n0 = blockIdx.y * 128;
  const int w = tid >> 6, lane = tid & 63;
  const int wr = (w >> 1) * 64, wc = (w & 1) * 64;
  const int g = lane >> 4, r = lane & 15;

  f32x4 acc[4][4] = {};

  for (int kb = 0; kb < NF; kb += 64) {
    __syncthreads();
#pragma unroll
    for (int i = 0; i < 4; ++i) {
      int c = i * 256 + tid;
      int row = c >> 3, slot = c & 7;
      int gs = slot ^ (row & 7);
      __builtin_amdgcn_global_load_lds(GPTR(A + (size_t)(m0 + row) * NF + kb + gs * 8),
                                       LPTR(As + c * 8), 16, 0, 0);
    }
#pragma unroll
    for (int i = 0; i < 4; ++i) {
      int c = i * 256 + tid;
      int row = c >> 3, slot = c & 7;
      int gs = slot ^ (row & 7);
      __builtin_amdgcn_global_load_lds(GPTR(W + (size_t)(n0 + row) * NF + kb + gs * 8),
                                       LPTR(Bs + c * 8), 16, 0, 0);
    }
    __syncthreads();
#pragma unroll
    for (int kk = 0; kk < 2; ++kk) {
      short8 af[4], bfr[4];
#pragma unroll
      for (int i = 0; i < 4; ++i) {
        int row = wr + i * 16 + r;
        int slot = (4 * kk + g) ^ (row & 7);
        af[i] = *reinterpret_cast<const short8*>(As + row * 64 + slot * 8);
      }
#pragma unroll
      for (int j = 0; j < 4; ++j) {
        int row = wc + j * 16 + r;
        int slot = (4 * kk + g) ^ (row & 7);
        bfr[j] = *reinterpret_cast<const short8*>(Bs + row * 64 + slot * 8);
      }
#pragma unroll
      for (int i = 0; i < 4; ++i)
#pragma unroll
        for (int j = 0; j < 4; ++j)
          acc[i][j] = __builtin_amdgcn_mfma_f32_16x16x32_bf16(af[i], bfr[j], acc[i][j], 0, 0, 0);
    }
  }
#pragma unroll
  for (int i = 0; i < 4; ++i)
#pragma unroll
    for (int j = 0; j < 4; ++j) {
      int grow = m0 + wr + i * 16 + 4 * g;
      int gcol = n0 + wc + j * 16 + r;
      float bv = bias[gcol];
#pragma unroll
      for (int reg = 0; reg < 4; ++reg)
        C[(size_t)(grow + reg) * NF + gcol] = f2bf((acc[i][j][reg] + bv) * 0.18033688f);
    }
}

// Flash attention, swapped-QK^T: 8 waves; block = ONE (b,h) x 512 q-rows (2 q-tiles
// of 256 per staged K/V tile). 256 blocks = 1/CU; K/V fetch bounded by construction.
// KVBLK=128 per barrier pair (2 x 64-kv subtiles). Reg-staged K+V with T14
// issue-early/write-late. K-frags/V-frags shared across q-tiles.
// launch_bounds(512,1): 1 block/CU resident (grid==256==CUs), VGPR cap 256 —
// (512,2)'s 128-VGPR cap caused ~150MB/dispatch scratch spill traffic in R7.
// LDS 32KB: K @0 (2 subtiles x 8KB; row kv 128B, 16B-slot s = granule s^P(kv),
//   P(r)=(r+(r>>3))&7, P(r+64)=P(r)); V @16384 (2 x 8KB; row d 128B, 8B-slot s =
//   kv-granule s^(d&15)^((d>>4)&3)).
__launch_bounds__(512, 1)
__global__ void attn_kernel(const u16t* __restrict__ Q, const u16t* __restrict__ K,
                            const u16t* __restrict__ V, const int* __restrict__ mask,
                            float* __restrict__ O) {
  __shared__ __attribute__((aligned(16))) char lds[32768];

  const int tid = threadIdx.x;
  const int lane = tid & 63;
  const int w = tid >> 6;
  const int qc = lane & 31;   // q-col for S^T / d-col for PV output
  const int hi = lane >> 5;
  const int b = blockIdx.x >> 4, h = blockIdx.x & 15;
  const size_t bbase = (size_t)b * TT * NF;
  const int hoff = h * DK;
  const int qrow0 = blockIdx.y * 512 + w * 32;   // q-tile 0; tile 1 at +256

  // Q B-frags (col=q=lane&31, k(d)=16t+8hi+e), both q-tiles, whole kernel
  short8 qa[2][4];
#pragma unroll
  for (int qt = 0; qt < 2; ++qt)
#pragma unroll
    for (int t = 0; t < 4; ++t)
      qa[qt][t] = *reinterpret_cast<const short8*>(
          Q + bbase + (size_t)(qrow0 + 256 * qt + qc) * NF + hoff + 16 * t + 8 * hi);

  f32x16 oacc[2][2] = {};
  float lsumA = 0.f, lsumB = 0.f;

  // K staging: chunk c = tid (subtile0 row tid>>3) and tid+512 (subtile1, +64)
  const int srow = tid >> 3;
  const int ksg = (tid & 7) ^ ((srow + (srow >> 3)) & 7);
  const u16t* Ksrc = K + bbase + (size_t)srow * NF + hoff + ksg * 8;

  // V staging: thread = (Qv = tid>>5, sub = (tid>>4)&1, dq = tid&15)
  const int Qv = tid >> 5, sub = (tid >> 4) & 1, dq = tid & 15;
  const u16t* Vsrc = V + bbase + (size_t)(4 * Qv + 2 * sub) * NF + hoff + 4 * dq;
  const int slotbase = Qv ^ (dq >> 2) ^ (4 * (dq & 3));
  const int wbase = 16384 + 4 * dq * 128 + (slotbase << 3) + 4 * sub;

  const int* msrc = mask + b * TT + lane;

  // read-address bases
  const int P0 = (qc + (qc >> 3)) & 7;
  const int P1 = (P0 + 4) & 7;
  const int kB0 = qc * 128 + ((hi ^ P0) << 4);         // K row qc
  const int kB1 = qc * 128 + 4096 + ((hi ^ P1) << 4);  // K row qc+32
  const int g0 = hi ^ (qc & 15) ^ ((qc >> 4) & 3);
  const int vRb0 = 16384 + qc * 128 + (g0 << 3);              // V col d=qc
  const int vRb1 = 16384 + (qc + 32) * 128 + ((g0 ^ 2) << 3); // V col d=qc+32

  // prologue: stage-0 loads into registers
  short8 kr0 = *reinterpret_cast<const short8*>(Ksrc);
  short8 kr1 = *reinterpret_cast<const short8*>(Ksrc + (size_t)64 * NF);
  uint2 uv0a = *reinterpret_cast<const uint2*>(Vsrc);
  uint2 uv0b = *reinterpret_cast<const uint2*>(Vsrc + NF);
  uint2 uv1a = *reinterpret_cast<const uint2*>(Vsrc + (size_t)64 * NF);
  uint2 uv1b = *reinterpret_cast<const uint2*>(Vsrc + (size_t)65 * NF);
  int mv0 = msrc[0], mv1 = msrc[64];
  Ksrc += (size_t)128 * NF; Vsrc += (size_t)128 * NF; msrc += 128;

  for (int s = 0; s < 16; ++s) {
    __syncthreads();  // prior stage's LDS readers done
    // write K (linear chunks) and V (b64-granule layout) from regs
    *reinterpret_cast<short8*>(lds + tid * 16) = kr0;
    *reinterpret_cast<short8*>(lds + tid * 16 + 8192) = kr1;
    {
      u32t p0 = (uv0a.x & 0xffffu) | (uv0b.x << 16);
      u32t p1 = (uv0a.x >> 16) | (uv0b.x & 0xffff0000u);
      u32t p2 = (uv0a.y & 0xffffu) | (uv0b.y << 16);
      u32t p3 = (uv0a.y >> 16) | (uv0b.y & 0xffff0000u);
      *reinterpret_cast<u32t*>(lds + (wbase ^ 0) + 0) = p0;
      *reinterpret_cast<u32t*>(lds + (wbase ^ 8) + 128) = p1;
      *reinterpret_cast<u32t*>(lds + (wbase ^ 16) + 256) = p2;
      *reinterpret_cast<u32t*>(lds + (wbase ^ 24) + 384) = p3;
      u32t q0 = (uv1a.x & 0xffffu) | (uv1b.x << 16);
      u32t q1 = (uv1a.x >> 16) | (uv1b.x & 0xffff0000u);
      u32t q2 = (uv1a.y & 0xffffu) | (uv1b.y << 16);
      u32t q3 = (uv1a.y >> 16) | (uv1b.y & 0xffff0000u);
      *reinterpret_cast<u32t*>(lds + ((wbase + 8192) ^ 0) + 0) = q0;
      *reinterpret_cast<u32t*>(lds + ((wbase + 8192) ^ 8) + 128) = q1;
      *reinterpret_cast<u32t*>(lds + ((wbase + 8192) ^ 16) + 256) = q2;
      *reinterpret_cast<u32t*>(lds + ((wbase + 8192) ^ 24) + 384) = q3;
    }
    unsigned long long bm0 = __ballot(mv0 != 0);
    unsigned long long bm1 = __ballot(mv1 != 0);
    __syncthreads();  // only ds_writes to drain — fast

    if (s != 15) {  // T14: issue next-stage loads; whole compute phase to land
      kr0 = *reinterpret_cast<const short8*>(Ksrc);
      kr1 = *reinterpret_cast<const short8*>(Ksrc + (size_t)64 * NF);
      uv0a = *reinterpret_cast<const uint2*>(Vsrc);
      uv0b = *reinterpret_cast<const uint2*>(Vsrc + NF);
      uv1a = *reinterpret_cast<const uint2*>(Vsrc + (size_t)64 * NF);
      uv1b = *reinterpret_cast<const uint2*>(Vsrc + (size_t)65 * NF);
      mv0 = msrc[0]; mv1 = msrc[64];
      Ksrc += (size_t)128 * NF; Vsrc += (size_t)128 * NF; msrc += 128;
    }

#pragma unroll
    for (int st = 0; st < 2; ++st) {
      const unsigned long long bm = st ? bm1 : bm0;
      const int rb = st * 8192;
      // QK^T: K-frags shared across both q-tiles
      f32x16 sA0 = {}, sA1 = {}, sB0 = {}, sB1 = {};
#pragma unroll
      for (int t = 0; t < 4; ++t) {
        short8 kf0 = *reinterpret_cast<const short8*>(lds + rb + (kB0 ^ (t << 5)));
        short8 kf1 = *reinterpret_cast<const short8*>(lds + rb + (kB1 ^ (t << 5)));
        sA0 = __builtin_amdgcn_mfma_f32_32x32x16_bf16(kf0, qa[0][t], sA0, 0, 0, 0);
        sA1 = __builtin_amdgcn_mfma_f32_32x32x16_bf16(kf1, qa[0][t], sA1, 0, 0, 0);
        sB0 = __builtin_amdgcn_mfma_f32_32x32x16_bf16(kf0, qa[1][t], sB0, 0, 0, 0);
        sB1 = __builtin_amdgcn_mfma_f32_32x32x16_bf16(kf1, qa[1][t], sB1, 0, 0, 0);
      }
      // softmax + pack + PV per kv-16-slice t; V-frags shared across q-tiles
#pragma unroll
      for (int t = 0; t < 4; ++t) {
        union { u32t u[4]; short8 s; } pA, pB;
        float eA = 0.f, eB = 0.f;
#pragma unroll
        for (int i = 0; i < 4; ++i) {
          const int reg = (t & 1) * 8 + 2 * i;
          const int kva = (reg & 3) + 8 * (reg >> 2) + 4 * hi + 32 * (t >> 1);
          const bool ma = (bm >> kva) & 1ull;
          const bool mb = (bm >> (kva + 1)) & 1ull;
          float xa = ma ? (t < 2 ? sA0[reg] : sA1[reg]) : -100.f;
          float xb = mb ? (t < 2 ? sA0[reg + 1] : sA1[reg + 1]) : -100.f;
          float ya = ma ? (t < 2 ? sB0[reg] : sB1[reg]) : -100.f;
          float yb = mb ? (t < 2 ? sB0[reg + 1] : sB1[reg + 1]) : -100.f;
          xa = __builtin_exp2f(xa); xb = __builtin_exp2f(xb);
          ya = __builtin_exp2f(ya); yb = __builtin_exp2f(yb);
          eA += xa + xb; eB += ya + yb;
          pA.u[i] = pkbf(xa, xb);
          pB.u[i] = pkbf(ya, yb);
        }
        lsumA += eA; lsumB += eB;
        union { uint2 u2[2]; short8 s; } vf0, vf1;
        vf0.u2[0] = *reinterpret_cast<const uint2*>(lds + ((vRb0 + rb) ^ ((4 * t) << 3)));
        vf0.u2[1] = *reinterpret_cast<const uint2*>(lds + ((vRb0 + rb) ^ (((4 * t) ^ 2) << 3)));
        vf1.u2[0] = *reinterpret_cast<const uint2*>(lds + ((vRb1 + rb) ^ ((4 * t) << 3)));
        vf1.u2[1] = *reinterpret_cast<const uint2*>(lds + ((vRb1 + rb) ^ (((4 * t) ^ 2) << 3)));
        oacc[0][0] = __builtin_amdgcn_mfma_f32_32x32x16_bf16(pA.s, vf0.s, oacc[0][0], 0, 0, 0);
        oacc[0][1] = __builtin_amdgcn_mfma_f32_32x32x16_bf16(pA.s, vf1.s, oacc[0][1], 0, 0, 0);
        oacc[1][0] = __builtin_amdgcn_mfma_f32_32x32x16_bf16(pB.s, vf0.s, oacc[1][0], 0, 0, 0);
        oacc[1][1] = __builtin_amdgcn_mfma_f32_32x32x16_bf16(pB.s, vf1.s, oacc[1][1], 0, 0, 0);
      }
    }
  }

  // O[q][d]: C-layout row = (reg&3)+8*(reg>>2)+4hi, col = qc (+32)
#pragma unroll
  for (int qt = 0; qt < 2; ++qt) {
    float lsq = qt ? lsumB : lsumA;
    float lall = lsq + __shfl_xor(lsq, 32, 64);
    float linv = 1.0f / lall;
#pragma unroll
    for (int reg = 0; reg < 16; ++reg) {
      const int crow = (reg & 3) + 8 * (reg >> 2) + 4 * hi;
      float rl = __shfl(linv, crow, 64);
      float* orow = O + bbase + (size_t)(qrow0 + 256 * qt + crow) * NF + hoff + qc;
      orow[0] = oacc[qt][0][reg] * rl;
      orow[32] = oacc[qt][1][reg] * rl;
    }
  }
}

extern "C" void kernel_launch(void* const* d_in, const int* in_sizes, int n_in,
                              void* d_out, int out_size, void* d_ws, size_t ws_size,
                              hipStream_t stream) {
  const float* query = (const float*)d_in[0];
  const float* key   = (const float*)d_in[1];
  const float* value = (const float*)d_in[2];
  const int*   mask  = (const int*)d_in[3];
  const float* Wq    = (const float*)d_in[4];
  const float* bq    = (const float*)d_in[5];
  float* out = (float*)d_out;

  u16t* ws = (u16t*)d_ws;
  u16t* qb = ws;
  u16t* kb = ws + (size_t)8 * 1024 * 1024;
  u16t* vb = ws + (size_t)16 * 1024 * 1024;
  u16t* wb = ws + (size_t)24 * 1024 * 1024;
  u16t* qp = ws + (size_t)25 * 1024 * 1024;

  cvt_kernel<<<2048, 256, 0, stream>>>(query, qb, (BT * NF) / 4);
  cvt_kernel<<<2048, 256, 0, stream>>>(key,   kb, (BT * NF) / 4);
  cvt_kernel<<<2048, 256, 0, stream>>>(value, vb, (BT * NF) / 4);
  cvt_kernel<<<1024, 256, 0, stream>>>(Wq,    wb, (NF * NF) / 4);

  qproj_kernel<<<dim3(BT / 128, NF / 128), 256, 0, stream>>>(qb, wb, bq, qp);
  // grid: x = (b,h), y = q-pair; 4 q-blocks of one (b,h) share an XCD (flat%8 = x%8)
  attn_kernel<<<dim3(BB * NHEAD, TT / 512), 512, 0, stream>>>(qp, kb, vb, mask, out);
}

// Round 9
// 170.360 us; speedup vs baseline: 1.5518x; 1.5501x over previous
//
#include <hip/hip_runtime.h>
#include <hip/hip_bf16.h>

#define GPTR(p) ((__attribute__((address_space(1))) void*)(p))
#define LPTR(p) ((__attribute__((address_space(3))) void*)(p))

typedef __attribute__((ext_vector_type(8))) short short8;
typedef __attribute__((ext_vector_type(4))) float f32x4;
typedef __attribute__((ext_vector_type(16))) float f32x16;
typedef unsigned short u16t;
typedef unsigned int u32t;

#define NHEAD 16
#define DK 64
#define NF 1024
#define BB 4
#define TT 2048
#define BT (BB * TT) /* 8192 */

static __device__ __forceinline__ u16t f2bf(float f) {
  union { float f; unsigned u; } c; c.f = f;
  unsigned r = c.u + 0x7fffu + ((c.u >> 16) & 1u);
  return (u16t)(r >> 16);
}

static __device__ __forceinline__ u32t pkbf(float a, float b) {
  float2 ff; ff.x = a; ff.y = b;
  __hip_bfloat162 h2 = __float22bfloat162_rn(ff);
  u32t uu; __builtin_memcpy(&uu, &h2, 4);
  return uu;
}

__global__ void cvt_kernel(const float* __restrict__ src, u16t* __restrict__ dst, int n4) {
  int stride = gridDim.x * blockDim.x;
  for (int i = blockIdx.x * blockDim.x + threadIdx.x; i < n4; i += stride) {
    float4 f = reinterpret_cast<const float4*>(src)[i];
    ushort4 o;
    o.x = f2bf(f.x); o.y = f2bf(f.y); o.z = f2bf(f.z); o.w = f2bf(f.w);
    reinterpret_cast<ushort4*>(dst)[i] = o;
  }
}

// C = (A @ W^T + bias) * 0.125 * log2(e) ; bf16 out, fp32 acc
__launch_bounds__(256, 2)
__global__ void qproj_kernel(const u16t* __restrict__ A, const u16t* __restrict__ W,
                             const float* __restrict__ bias, u16t* __restrict__ C) {
  __shared__ u16t As[128 * 64];
  __shared__ u16t Bs[128 * 64];
  const int tid = threadIdx.x;
  const int m0 = blockIdx.x * 128;
  const int n0 = blockIdx.y * 128;
  const int w = tid >> 6, lane = tid & 63;
  const int wr = (w >> 1) * 64, wc = (w & 1) * 64;
  const int g = lane >> 4, r = lane & 15;

  f32x4 acc[4][4] = {};

  for (int kb = 0; kb < NF; kb += 64) {
    __syncthreads();
#pragma unroll
    for (int i = 0; i < 4; ++i) {
      int c = i * 256 + tid;
      int row = c >> 3, slot = c & 7;
      int gs = slot ^ (row & 7);
      __builtin_amdgcn_global_load_lds(GPTR(A + (size_t)(m0 + row) * NF + kb + gs * 8),
                                       LPTR(As + c * 8), 16, 0, 0);
    }
#pragma unroll
    for (int i = 0; i < 4; ++i) {
      int c = i * 256 + tid;
      int row = c >> 3, slot = c & 7;
      int gs = slot ^ (row & 7);
      __builtin_amdgcn_global_load_lds(GPTR(W + (size_t)(n0 + row) * NF + kb + gs * 8),
                                       LPTR(Bs + c * 8), 16, 0, 0);
    }
    __syncthreads();
#pragma unroll
    for (int kk = 0; kk < 2; ++kk) {
      short8 af[4], bfr[4];
#pragma unroll
      for (int i = 0; i < 4; ++i) {
        int row = wr + i * 16 + r;
        int slot = (4 * kk + g) ^ (row & 7);
        af[i] = *reinterpret_cast<const short8*>(As + row * 64 + slot * 8);
      }
#pragma unroll
      for (int j = 0; j < 4; ++j) {
        int row = wc + j * 16 + r;
        int slot = (4 * kk + g) ^ (row & 7);
        bfr[j] = *reinterpret_cast<const short8*>(Bs + row * 64 + slot * 8);
      }
#pragma unroll
      for (int i = 0; i < 4; ++i)
#pragma unroll
        for (int j = 0; j < 4; ++j)
          acc[i][j] = __builtin_amdgcn_mfma_f32_16x16x32_bf16(af[i], bfr[j], acc[i][j], 0, 0, 0);
    }
  }
#pragma unroll
  for (int i = 0; i < 4; ++i)
#pragma unroll
    for (int j = 0; j < 4; ++j) {
      int grow = m0 + wr + i * 16 + 4 * g;
      int gcol = n0 + wc + j * 16 + r;
      float bv = bias[gcol];
#pragma unroll
      for (int reg = 0; reg < 4; ++reg)
        C[(size_t)(grow + reg) * NF + gcol] = f2bf((acc[i][j][reg] + bv) * 0.18033688f);
    }
}

// Flash attention, swapped-QK^T: 8 waves; block = ONE (b,h) x 512 q-rows (2 q-tiles
// of 256 per staged K/V tile). 256 blocks = 1/CU; K/V fetch bounded by construction.
// R6 layouts/k-maps/register-profile, but ONE raw barrier per tile (m201 pattern):
//   ds_write V(t) -> s_waitcnt vmcnt(0) lgkmcnt(0) -> s_barrier ->
//   issue K-DMA(t+1) + V-loads(t+1) (full compute phase to land) -> compute(t).
// LDS 32KB: K dbuf @0/@8192 (row kv 128B, 16B-slot s = granule s^P(kv),
//   P(r)=(r+(r>>3))&7); V dbuf @16384/@24576 (row d 128B, 8B-slot s = kv-granule
//   s^(d&15)^((d>>4)&3)).
__launch_bounds__(512, 2)
__global__ void attn_kernel(const u16t* __restrict__ Q, const u16t* __restrict__ K,
                            const u16t* __restrict__ V, const int* __restrict__ mask,
                            float* __restrict__ O) {
  __shared__ __attribute__((aligned(16))) char lds[32768];

  const int tid = threadIdx.x;
  const int lane = tid & 63;
  const int w = tid >> 6;
  const int qc = lane & 31;   // q-col for S^T / d-col for PV output
  const int hi = lane >> 5;
  const int b = blockIdx.x >> 4, h = blockIdx.x & 15;
  const size_t bbase = (size_t)b * TT * NF;
  const int hoff = h * DK;
  const int qrow0 = blockIdx.y * 512 + w * 32;   // q-tile 0; tile 1 at +256

  // Q B-frags (col=q=lane&31, k(d)=16t+8hi+e), both q-tiles, whole kernel
  short8 qa[2][4];
#pragma unroll
  for (int qt = 0; qt < 2; ++qt)
#pragma unroll
    for (int t = 0; t < 4; ++t)
      qa[qt][t] = *reinterpret_cast<const short8*>(
          Q + bbase + (size_t)(qrow0 + 256 * qt + qc) * NF + hoff + 16 * t + 8 * hi);

  f32x16 oacc[2][2] = {};
  float lsumA = 0.f, lsumB = 0.f;

  // K staging (DMA): chunk = tid, row = tid>>3, pre-swizzled source
  const int srow = tid >> 3;
  const int ksg = (tid & 7) ^ ((srow + (srow >> 3)) & 7);
  const u16t* Ksrc = K + bbase + (size_t)srow * NF + hoff + ksg * 8;

  // V staging: thread = (Qv = tid>>5, sub = (tid>>4)&1, dq = tid&15)
  const int Qv = tid >> 5, sub = (tid >> 4) & 1, dq = tid & 15;
  const u16t* Vsrc = V + bbase + (size_t)(4 * Qv + 2 * sub) * NF + hoff + 4 * dq;
  const int slotbase = Qv ^ (dq >> 2) ^ (4 * (dq & 3));
  const int wbase = 4 * dq * 128 + (slotbase << 3) + 4 * sub;  // within V buffer

  const int* msrc = mask + b * TT + lane;

  // read-address bases (within buffers)
  const int P0 = (qc + (qc >> 3)) & 7;
  const int P1 = (P0 + 4) & 7;
  const int kB0 = qc * 128 + ((hi ^ P0) << 4);         // K row qc
  const int kB1 = qc * 128 + 4096 + ((hi ^ P1) << 4);  // K row qc+32
  const int g0 = hi ^ (qc & 15) ^ ((qc >> 4) & 3);
  const int vRb0 = qc * 128 + (g0 << 3);               // V col d=qc
  const int vRb1 = (qc + 32) * 128 + ((g0 ^ 2) << 3);  // V col d=qc+32

  // prologue: K(0) DMA -> K0; V(0)/mask(0) -> regs
  __builtin_amdgcn_global_load_lds(GPTR(Ksrc), LPTR(lds + tid * 16), 16, 0, 0);
  Ksrc += (size_t)64 * NF;
  uint2 va = *reinterpret_cast<const uint2*>(Vsrc);
  uint2 vbl = *reinterpret_cast<const uint2*>(Vsrc + NF);
  Vsrc += (size_t)64 * NF;
  int mv = msrc[0];

  for (int t2 = 0; t2 < TT; t2 += 64) {
    const int cb = (t2 >> 6) & 1;
    const int kbb = cb * 8192;          // current K buffer
    const int vbb = 16384 + cb * 8192;  // current V buffer

    { // write V(t) into V[cb] (conflicts only with compute(t-2): safe)
      u32t p0 = (va.x & 0xffffu) | (vbl.x << 16);
      u32t p1 = (va.x >> 16) | (vbl.x & 0xffff0000u);
      u32t p2 = (va.y & 0xffffu) | (vbl.y << 16);
      u32t p3 = (va.y >> 16) | (vbl.y & 0xffff0000u);
      *reinterpret_cast<u32t*>(lds + vbb + (wbase ^ 0) + 0) = p0;
      *reinterpret_cast<u32t*>(lds + vbb + (wbase ^ 8) + 128) = p1;
      *reinterpret_cast<u32t*>(lds + vbb + (wbase ^ 16) + 256) = p2;
      *reinterpret_cast<u32t*>(lds + vbb + (wbase ^ 24) + 384) = p3;
    }
    unsigned long long bm = __ballot(mv != 0);
    // counted-wait barrier: K-DMA(t) and V writes drained; all are a full
    // compute-phase old in steady state.
    asm volatile("s_waitcnt vmcnt(0) lgkmcnt(0)" ::: "memory");
    __builtin_amdgcn_s_barrier();

    if (t2 + 64 < TT) {  // prefetch t+1: entire compute(t) to land
      __builtin_amdgcn_global_load_lds(GPTR(Ksrc), LPTR(lds + (kbb ^ 8192) + tid * 16), 16, 0, 0);
      Ksrc += (size_t)64 * NF;
      va = *reinterpret_cast<const uint2*>(Vsrc);
      vbl = *reinterpret_cast<const uint2*>(Vsrc + NF);
      Vsrc += (size_t)64 * NF;
      mv = msrc[t2 + 64];
    }

    // QK^T: K-frags shared across both q-tiles
    f32x16 sA0 = {}, sA1 = {}, sB0 = {}, sB1 = {};
#pragma unroll
    for (int t = 0; t < 4; ++t) {
      short8 kf0 = *reinterpret_cast<const short8*>(lds + kbb + (kB0 ^ (t << 5)));
      short8 kf1 = *reinterpret_cast<const short8*>(lds + kbb + (kB1 ^ (t << 5)));
      sA0 = __builtin_amdgcn_mfma_f32_32x32x16_bf16(kf0, qa[0][t], sA0, 0, 0, 0);
      sA1 = __builtin_amdgcn_mfma_f32_32x32x16_bf16(kf1, qa[0][t], sA1, 0, 0, 0);
      sB0 = __builtin_amdgcn_mfma_f32_32x32x16_bf16(kf0, qa[1][t], sB0, 0, 0, 0);
      sB1 = __builtin_amdgcn_mfma_f32_32x32x16_bf16(kf1, qa[1][t], sB1, 0, 0, 0);
    }

    // softmax + pack + PV per kv-16-slice t; V-frags shared across q-tiles
    const u32t bmlo = (u32t)(bm >> (4 * hi));
    const u32t bmhi = (u32t)(bm >> (32 + 4 * hi));
#pragma unroll
    for (int t = 0; t < 4; ++t) {
      const u32t bms = (t < 2) ? bmlo : bmhi;
      union { u32t u[4]; short8 s; } pA, pB;
      float eA = 0.f, eB = 0.f;
#pragma unroll
      for (int i = 0; i < 4; ++i) {
        const int reg = (t & 1) * 8 + 2 * i;
        const int bit = (reg & 3) + 8 * (reg >> 2);
        const bool ma = (bms >> bit) & 1u;
        const bool mb = (bms >> (bit + 1)) & 1u;
        float xa = ma ? (t < 2 ? sA0[reg] : sA1[reg]) : -100.f;
        float xb = mb ? (t < 2 ? sA0[reg + 1] : sA1[reg + 1]) : -100.f;
        float ya = ma ? (t < 2 ? sB0[reg] : sB1[reg]) : -100.f;
        float yb = mb ? (t < 2 ? sB0[reg + 1] : sB1[reg + 1]) : -100.f;
        xa = __builtin_exp2f(xa); xb = __builtin_exp2f(xb);
        ya = __builtin_exp2f(ya); yb = __builtin_exp2f(yb);
        eA += xa + xb; eB += ya + yb;
        pA.u[i] = pkbf(xa, xb);
        pB.u[i] = pkbf(ya, yb);
      }
      lsumA += eA; lsumB += eB;
      union { uint2 u2[2]; short8 s; } vf0, vf1;
      vf0.u2[0] = *reinterpret_cast<const uint2*>(lds + vbb + (vRb0 ^ ((4 * t) << 3)));
      vf0.u2[1] = *reinterpret_cast<const uint2*>(lds + vbb + (vRb0 ^ (((4 * t) ^ 2) << 3)));
      vf1.u2[0] = *reinterpret_cast<const uint2*>(lds + vbb + (vRb1 ^ ((4 * t) << 3)));
      vf1.u2[1] = *reinterpret_cast<const uint2*>(lds + vbb + (vRb1 ^ (((4 * t) ^ 2) << 3)));
      oacc[0][0] = __builtin_amdgcn_mfma_f32_32x32x16_bf16(pA.s, vf0.s, oacc[0][0], 0, 0, 0);
      oacc[0][1] = __builtin_amdgcn_mfma_f32_32x32x16_bf16(pA.s, vf1.s, oacc[0][1], 0, 0, 0);
      oacc[1][0] = __builtin_amdgcn_mfma_f32_32x32x16_bf16(pB.s, vf0.s, oacc[1][0], 0, 0, 0);
      oacc[1][1] = __builtin_amdgcn_mfma_f32_32x32x16_bf16(pB.s, vf1.s, oacc[1][1], 0, 0, 0);
    }
  }

  // O[q][d]: C-layout row = (reg&3)+8*(reg>>2)+4hi, col = qc (+32)
#pragma unroll
  for (int qt = 0; qt < 2; ++qt) {
    float lsq = qt ? lsumB : lsumA;
    float lall = lsq + __shfl_xor(lsq, 32, 64);
    float linv = 1.0f / lall;
#pragma unroll
    for (int reg = 0; reg < 16; ++reg) {
      const int crow = (reg & 3) + 8 * (reg >> 2) + 4 * hi;
      float rl = __shfl(linv, crow, 64);
      float* orow = O + bbase + (size_t)(qrow0 + 256 * qt + crow) * NF + hoff + qc;
      orow[0] = oacc[qt][0][reg] * rl;
      orow[32] = oacc[qt][1][reg] * rl;
    }
  }
}

extern "C" void kernel_launch(void* const* d_in, const int* in_sizes, int n_in,
                              void* d_out, int out_size, void* d_ws, size_t ws_size,
                              hipStream_t stream) {
  const float* query = (const float*)d_in[0];
  const float* key   = (const float*)d_in[1];
  const float* value = (const float*)d_in[2];
  const int*   mask  = (const int*)d_in[3];
  const float* Wq    = (const float*)d_in[4];
  const float* bq    = (const float*)d_in[5];
  float* out = (float*)d_out;

  u16t* ws = (u16t*)d_ws;
  u16t* qb = ws;
  u16t* kb = ws + (size_t)8 * 1024 * 1024;
  u16t* vb = ws + (size_t)16 * 1024 * 1024;
  u16t* wb = ws + (size_t)24 * 1024 * 1024;
  u16t* qp = ws + (size_t)25 * 1024 * 1024;

  cvt_kernel<<<2048, 256, 0, stream>>>(query, qb, (BT * NF) / 4);
  cvt_kernel<<<2048, 256, 0, stream>>>(key,   kb, (BT * NF) / 4);
  cvt_kernel<<<2048, 256, 0, stream>>>(value, vb, (BT * NF) / 4);
  cvt_kernel<<<1024, 256, 0, stream>>>(Wq,    wb, (NF * NF) / 4);

  qproj_kernel<<<dim3(BT / 128, NF / 128), 256, 0, stream>>>(qb, wb, bq, qp);
  // grid: x = (b,h), y = q-pair; 4 q-blocks of one (b,h) share an XCD (flat%8 = x%8)
  attn_kernel<<<dim3(BB * NHEAD, TT / 512), 512, 0, stream>>>(qp, kb, vb, mask, out);
}